// Round 25
// baseline (391.244 us; speedup 1.0000x reference)
//
#include <hip/hip_runtime.h>

#define DEV __device__ __forceinline__

typedef __attribute__((ext_vector_type(8))) short short8;
typedef __attribute__((ext_vector_type(4))) float f32x4;
typedef __attribute__((ext_vector_type(4))) unsigned u32x4;

DEV unsigned short f2b(float f){
  unsigned r;
  asm("v_cvt_pk_bf16_f32 %0, %1, %1" : "=v"(r) : "v"(f));
  return (unsigned short)r;
}
DEV unsigned cvt_pk2(float lo, float hi){
  unsigned r;
  asm("v_cvt_pk_bf16_f32 %0, %1, %2" : "=v"(r) : "v"(lo), "v"(hi));
  return r;
}
DEV float b2f(unsigned short u){ unsigned v = ((unsigned)u)<<16; float f; __builtin_memcpy(&f,&v,4); return f; }

DEV void gload_lds16(const void* g, void* l){
  __builtin_amdgcn_global_load_lds((const __attribute__((address_space(1))) void*)g,
                                   (__attribute__((address_space(3))) void*)l, 16, 0, 0);
}

#define SCL 0.18033688011112042f   /* 0.125 * log2(e) */

// ---------------- f32 -> bf16 elementwise ----------------
__global__ __launch_bounds__(256) void cvt_f32_bf16(
    const float* __restrict__ in, unsigned short* __restrict__ out, int n)
{
  int i = (blockIdx.x*256 + threadIdx.x)*4;
  if (i >= n) return;
  float4 v = *(const float4*)(in + i);
  uint2 o;
  o.x = cvt_pk2(v.x, v.y);
  o.y = cvt_pk2(v.z, v.w);
  *(uint2*)(out + i) = o;
}

// ---------------- batched transpose+convert: Wt[n*K+k] = bf16(W[k*N+n]) ----------------
struct TransAll {
  const float* W[10]; unsigned short* Wt[10];
  int K[10], N[10], swapxy[10];
};
__global__ __launch_bounds__(256) void transpose_cvt_all(TransAll p)
{
  const int z = blockIdx.z;
  const int bx = p.swapxy[z] ? blockIdx.y : blockIdx.x;
  const int by = p.swapxy[z] ? blockIdx.x : blockIdx.y;
  const int K = p.K[z], N = p.N[z];
  const int n0 = bx*32, k0 = by*32;
  if (n0 >= N || k0 >= K) return;
  const float* __restrict__ W = p.W[z];
  unsigned short* __restrict__ Wt = p.Wt[z];
  __shared__ float tile[32][33];
  int tx = threadIdx.x & 31, ty = threadIdx.x >> 5;
  #pragma unroll
  for (int j=0;j<32;j+=8)
    tile[ty+j][tx] = W[(size_t)(k0+ty+j)*N + n0+tx];
  __syncthreads();
  #pragma unroll
  for (int j=0;j<32;j+=8)
    Wt[(size_t)(n0+ty+j)*K + k0+tx] = f2b(tile[tx][ty+j]);
}

// ---------------- GEMM 128x128, BK=64, swizzled LDS (conflict-free reads) ----------------
// K-split via blockIdx.z: chunks 0,1 -> C + z*M*N ; chunks 2,3 -> C2 + (z-2)*M*N.
template<int EPI>
__global__ __launch_bounds__(256) void gemm_bt(
    const unsigned short* __restrict__ A,
    const unsigned short* __restrict__ Bt,
    const float* __restrict__ bias,
    unsigned short* __restrict__ C,
    unsigned short* __restrict__ C2,
    int M, int N, int Kc, int LDA, int LDB)
{
  __shared__ alignas(16) unsigned short Asm_[128*64];
  __shared__ alignas(16) unsigned short Bsm_[128*64];
  const int tid = threadIdx.x;
  const int wave = tid>>6, lane = tid&63;
  const int r0 = lane&15, kq = (lane>>4)*8, cq = lane>>4;
  const int m0 = blockIdx.y*128, n0 = blockIdx.x*128;
  const int wr = wave>>1, wc = wave&1;
  const int koff = blockIdx.z * Kc;
  const bool addb = (blockIdx.z == 0);
  unsigned short* __restrict__ Cb =
      (blockIdx.z < 2) ? (C  + (size_t)blockIdx.z     * M * N)
                       : (C2 + (size_t)(blockIdx.z-2) * M * N);
  const int swr = (r0&7)<<3;

  f32x4 zero4 = {0.f,0.f,0.f,0.f};
  f32x4 acc[4][4];
  #pragma unroll
  for (int m=0;m<4;m++)
    #pragma unroll
    for (int n=0;n<4;n++) acc[m][n]=zero4;

  const int nk = Kc>>6;
  for (int kt=0; kt<nk; kt++){
    #pragma unroll
    for (int i=0;i<4;i++){
      int idx = i*256 + tid;
      int row = idx>>3;
      int sc = ((idx&7) ^ (row&7))<<3;
      gload_lds16(A  + (size_t)(m0+row)*LDA + koff + (kt<<6) + sc, Asm_ + (size_t)idx*8);
      gload_lds16(Bt + (size_t)(n0+row)*LDB + koff + (kt<<6) + sc, Bsm_ + (size_t)idx*8);
    }
    __syncthreads();
    #pragma unroll
    for (int kk=0;kk<2;kk++){
      short8 a[4], b[4];
      #pragma unroll
      for (int m=0;m<4;m++)
        a[m] = *(const short8*)&Asm_[(((wr*64 + m*16 + r0)*64) + kk*32 + kq) ^ swr];
      #pragma unroll
      for (int n=0;n<4;n++)
        b[n] = *(const short8*)&Bsm_[(((wc*64 + n*16 + r0)*64) + kk*32 + kq) ^ swr];
      #pragma unroll
      for (int m=0;m<4;m++)
        #pragma unroll
        for (int n=0;n<4;n++)
          acc[m][n] = __builtin_amdgcn_mfma_f32_16x16x32_bf16(a[m], b[n], acc[m][n], 0,0,0);
    }
    __syncthreads();
  }

  #pragma unroll
  for (int n=0;n<4;n++){
    int col = n0 + wc*64 + n*16 + r0;
    float bs = addb ? bias[col] : 0.f;
    #pragma unroll
    for (int m=0;m<4;m++){
      int rowb = m0 + wr*64 + m*16 + cq*4;
      #pragma unroll
      for (int reg=0;reg<4;reg++){
        float v = acc[m][n][reg] + bs;
        if (EPI==1) v = fmaxf(v, 0.f);
        Cb[(size_t)(rowb+reg)*N + col] = f2b(v);
      }
    }
  }
}

// ---------------- fused QKV GEMM (128x128, BK=64, swizzled; N=3072, per-which A) ----------------
struct QKVArgs { const unsigned short* Aw[3]; const float* bias[3]; unsigned short* out[3]; };
__global__ __launch_bounds__(256) void gemm_qkv(
    const unsigned short* __restrict__ Bt,
    QKVArgs args, int M, int K)
{
  __shared__ alignas(16) unsigned short Asm_[128*64];
  __shared__ alignas(16) unsigned short Bsm_[128*64];
  const int tid = threadIdx.x;
  const int wave = tid>>6, lane = tid&63;
  const int r0 = lane&15, kq = (lane>>4)*8, cq = lane>>4;
  const int m0 = blockIdx.y*128, n0 = blockIdx.x*128;
  const int wr = wave>>1, wc = wave&1;
  const int which = n0>>10;
  const unsigned short* __restrict__ A = args.Aw[which];
  const int swr = (r0&7)<<3;

  f32x4 zero4 = {0.f,0.f,0.f,0.f};
  f32x4 acc[4][4];
  #pragma unroll
  for (int m=0;m<4;m++)
    #pragma unroll
    for (int n=0;n<4;n++) acc[m][n]=zero4;

  const int nk = K>>6;
  for (int kt=0; kt<nk; kt++){
    #pragma unroll
    for (int i=0;i<4;i++){
      int idx = i*256 + tid;
      int row = idx>>3;
      int sc = ((idx&7) ^ (row&7))<<3;
      gload_lds16(A  + (size_t)(m0+row)*K + (kt<<6) + sc, Asm_ + (size_t)idx*8);
      gload_lds16(Bt + (size_t)(n0+row)*K + (kt<<6) + sc, Bsm_ + (size_t)idx*8);
    }
    __syncthreads();
    #pragma unroll
    for (int kk=0;kk<2;kk++){
      short8 a[4], b[4];
      #pragma unroll
      for (int m=0;m<4;m++)
        a[m] = *(const short8*)&Asm_[(((wr*64 + m*16 + r0)*64) + kk*32 + kq) ^ swr];
      #pragma unroll
      for (int n=0;n<4;n++)
        b[n] = *(const short8*)&Bsm_[(((wc*64 + n*16 + r0)*64) + kk*32 + kq) ^ swr];
      #pragma unroll
      for (int m=0;m<4;m++)
        #pragma unroll
        for (int n=0;n<4;n++)
          acc[m][n] = __builtin_amdgcn_mfma_f32_16x16x32_bf16(a[m], b[n], acc[m][n], 0,0,0);
    }
    __syncthreads();
  }

  const int n0l = n0 & 1023;
  unsigned short* __restrict__ Cout = args.out[which];
  const float* __restrict__ bp = args.bias[which];
  const bool isV = (which == 2);
  const float scl = (which == 0) ? SCL : 1.f;

  #pragma unroll
  for (int n=0;n<4;n++){
    int col = n0l + wc*64 + n*16 + r0;
    float bs = bp[col];
    int h_ = col>>6, dk = col&63;
    #pragma unroll
    for (int m=0;m<4;m++){
      int rowb = m0 + wr*64 + m*16 + cq*4;
      #pragma unroll
      for (int reg=0;reg<4;reg++){
        float v = (acc[m][n][reg] + bs) * scl;
        int row = rowb + reg;
        int b_ = row>>11, s_ = row&2047;
        if (isV){
          int sp = (s_ & ~31) | (((s_>>2)&3)<<3) | (((s_>>4)&1)<<2) | (s_&3);
          Cout[(((size_t)(b_*16+h_))*64 + dk)*2048 + sp] = f2b(v);
        } else {
          Cout[(((size_t)(b_*16+h_))*2048 + s_)*64 + dk] = f2b(v);
        }
      }
    }
  }
}

// ---------------- causal flash attention (QB=64, proven) ----------------
__global__ __launch_bounds__(256, 4) void attn_causal(
    const unsigned short* __restrict__ Q,
    const unsigned short* __restrict__ K,
    const unsigned short* __restrict__ Vt,
    unsigned short* __restrict__ O,
    float* __restrict__ po, float* __restrict__ ml)
{
  __shared__ alignas(16) unsigned short Ksm[2][64*64];
  __shared__ alignas(16) unsigned short Vsm[2][64*64];
  const int S = 2048, DK = 64;
  const int h = blockIdx.y, b = blockIdx.z;
  const int tid = threadIdx.x, wave = tid>>6, lane = tid&63;
  const int r0 = lane&15, kq = (lane>>4)*8, cq = lane>>4;

  int qb, t0, t1, chunk = 0;
  bool partial = false;
  {
    int bx = blockIdx.x;
    if (bx < 32){ qb = bx; t0 = 0; t1 = (qb<15?qb:15); chunk = 0; partial = (qb>=16); }
    else        { qb = bx-16; t0 = 16; t1 = qb; chunk = 1; partial = true; }
  }

  const unsigned short* qh = Q  + ((size_t)(b*16+h))*S*DK;
  const unsigned short* kh = K  + ((size_t)(b*16+h))*S*DK;
  const unsigned short* vh = Vt + ((size_t)(b*16+h))*DK*S;

  const int idx0 = tid, idx1 = 256 + tid;
  const int row0 = idx0>>3, row1 = idx1>>3;
  const int cb0 = ((idx0&7) ^ (row0&7))<<3;
  const int cb1 = ((idx1&7) ^ (row1&7))<<3;
  const unsigned short* kg0 = kh + (size_t)row0*64 + cb0;
  const unsigned short* kg1 = kh + (size_t)row1*64 + cb1;
  const unsigned short* vg0 = vh + (size_t)row0*2048 + cb0;
  const unsigned short* vg1 = vh + (size_t)row1*2048 + cb1;
  const int ld0 = wave*512, ld1 = 2048 + wave*512;
  const int swr = (r0&7)<<3;

  short8 qa[2];
  {
    int qrow = qb*64 + wave*16 + r0;
    qa[0] = *(const short8*)&qh[(size_t)qrow*DK + kq];
    qa[1] = *(const short8*)&qh[(size_t)qrow*DK + 32 + kq];
  }
  short8 vones;
  #pragma unroll
  for (int j=0;j<8;j++) vones[j] = (short)0x3F80;

  f32x4 zero4 = {0.f,0.f,0.f,0.f};
  f32x4 o[4];
  float lr = 0.f;
  #pragma unroll
  for (int n=0;n<4;n++) o[n]=zero4;

  gload_lds16(kg0 + (size_t)t0*4096, &Ksm[0][ld0]);
  gload_lds16(kg1 + (size_t)t0*4096, &Ksm[0][ld1]);
  gload_lds16(vg0 + (size_t)t0*64,   &Vsm[0][ld0]);
  gload_lds16(vg1 + (size_t)t0*64,   &Vsm[0][ld1]);

  int cur = 0;
  for (int t=t0; t<=t1; t++){
    if (t < t1){
      gload_lds16(kg0 + (size_t)(t+1)*4096, &Ksm[cur^1][ld0]);
      gload_lds16(kg1 + (size_t)(t+1)*4096, &Ksm[cur^1][ld1]);
      gload_lds16(vg0 + (size_t)(t+1)*64,   &Vsm[cur^1][ld0]);
      gload_lds16(vg1 + (size_t)(t+1)*64,   &Vsm[cur^1][ld1]);
      asm volatile("s_waitcnt vmcnt(4)" ::: "memory");
    } else {
      asm volatile("s_waitcnt vmcnt(0)" ::: "memory");
    }
    __builtin_amdgcn_s_barrier();
    asm volatile("" ::: "memory");

    f32x4 sv[4];
    #pragma unroll
    for (int n=0;n<4;n++) sv[n]=zero4;
    #pragma unroll
    for (int n=0;n<4;n++)
      #pragma unroll
      for (int kk=0;kk<2;kk++){
        short8 kb = *(const short8*)&Ksm[cur][(((n*16 + r0)*64) + kk*32 + kq) ^ swr];
        sv[n] = __builtin_amdgcn_mfma_f32_16x16x32_bf16(kb, qa[kk], sv[n], 0,0,0);
      }
    if (t==qb){
      const int qg = wave*16 + r0;
      #pragma unroll
      for (int n=0;n<4;n++)
        #pragma unroll
        for (int reg=0;reg<4;reg++){
          if (n*16 + cq*4 + reg > qg) sv[n][reg] += -1000000000.0f;
        }
    }

    #pragma unroll
    for (int n=0;n<4;n++)
      #pragma unroll
      for (int reg=0;reg<4;reg++)
        sv[n][reg] = exp2f(sv[n][reg]);

    short8 pa[2];
    #pragma unroll
    for (int kk=0;kk<2;kk++){
      u32x4 w;
      w[0] = cvt_pk2(sv[2*kk][0],   sv[2*kk][1]);
      w[1] = cvt_pk2(sv[2*kk][2],   sv[2*kk][3]);
      w[2] = cvt_pk2(sv[2*kk+1][0], sv[2*kk+1][1]);
      w[3] = cvt_pk2(sv[2*kk+1][2], sv[2*kk+1][3]);
      pa[kk] = __builtin_bit_cast(short8, w);
    }

    {
      f32x4 ls = zero4;
      ls = __builtin_amdgcn_mfma_f32_16x16x32_bf16(vones, pa[0], ls, 0,0,0);
      ls = __builtin_amdgcn_mfma_f32_16x16x32_bf16(vones, pa[1], ls, 0,0,0);
      lr += ls[0];
    }

    #pragma unroll
    for (int n=0;n<4;n++)
      #pragma unroll
      for (int kk=0;kk<2;kk++){
        short8 vb = *(const short8*)&Vsm[cur][(((n*16 + r0)*64) + kk*32 + cq*8) ^ swr];
        o[n] = __builtin_amdgcn_mfma_f32_16x16x32_bf16(vb, pa[kk], o[n], 0,0,0);
      }

    asm volatile("" ::: "memory");
    __builtin_amdgcn_s_barrier();
    asm volatile("" ::: "memory");
    cur ^= 1;
  }

  if (partial){
    float* pop = po + (size_t)chunk*2097152;
    float* mlp = ml + (size_t)chunk*32768;
    const int bh = b*16 + h, qb16 = qb - 16;
    const int rowIdx = (bh*16 + qb16)*64 + wave*16 + r0;
    if (cq == 0) mlp[rowIdx] = lr;
    #pragma unroll
    for (int n=0;n<4;n++){
      float4 v; v.x=o[n][0]; v.y=o[n][1]; v.z=o[n][2]; v.w=o[n][3];
      *(float4*)&pop[(size_t)rowIdx*64 + n*16 + cq*4] = v;
    }
  } else {
    const int sg = qb*64 + wave*16 + r0;
    const float inv = 1.f / lr;
    unsigned short* op = O + ((size_t)b*S + sg)*1024 + h*64;
    #pragma unroll
    for (int n=0;n<4;n++){
      uint2 w;
      w.x = cvt_pk2(o[n][0]*inv, o[n][1]*inv);
      w.y = cvt_pk2(o[n][2]*inv, o[n][3]*inv);
      *(uint2*)(op + n*16 + cq*4) = w;
    }
  }
}

// ---------------- cross attention: QB=128 (2 q-subtiles share staged K/V) ----------------
__global__ __launch_bounds__(256, 2) void attn_cross2(
    const unsigned short* __restrict__ Q,
    const unsigned short* __restrict__ K,
    const unsigned short* __restrict__ Vt,
    unsigned short* __restrict__ pob,
    float* __restrict__ ml)
{
  __shared__ alignas(16) unsigned short Ksm[2][64*64];
  __shared__ alignas(16) unsigned short Vsm[2][64*64];
  const int S = 2048, DK = 64;
  const int h = blockIdx.y, b = blockIdx.z;
  const int tid = threadIdx.x, wave = tid>>6, lane = tid&63;
  const int r0 = lane&15, kq = (lane>>4)*8, cq = lane>>4;

  int qB, t0, t1, chunk;
  {
    int bx = blockIdx.x;
    if (bx < 16){ qB = bx; t0 = 0; t1 = 15; chunk = 0; }
    else        { qB = bx-16; t0 = 16; t1 = 31; chunk = 1; }
  }

  const unsigned short* qh = Q  + ((size_t)(b*16+h))*S*DK;
  const unsigned short* kh = K  + ((size_t)(b*16+h))*S*DK;
  const unsigned short* vh = Vt + ((size_t)(b*16+h))*DK*S;

  const int idx0 = tid, idx1 = 256 + tid;
  const int row0 = idx0>>3, row1 = idx1>>3;
  const int cb0 = ((idx0&7) ^ (row0&7))<<3;
  const int cb1 = ((idx1&7) ^ (row1&7))<<3;
  const unsigned short* kg0 = kh + (size_t)row0*64 + cb0;
  const unsigned short* kg1 = kh + (size_t)row1*64 + cb1;
  const unsigned short* vg0 = vh + (size_t)row0*2048 + cb0;
  const unsigned short* vg1 = vh + (size_t)row1*2048 + cb1;
  const int ld0 = wave*512, ld1 = 2048 + wave*512;
  const int swr = (r0&7)<<3;

  short8 qa0[2], qa1[2];
  {
    int qrow = qB*128 + wave*16 + r0;
    qa0[0] = *(const short8*)&qh[(size_t)qrow*DK + kq];
    qa0[1] = *(const short8*)&qh[(size_t)qrow*DK + 32 + kq];
    qa1[0] = *(const short8*)&qh[(size_t)(qrow+64)*DK + kq];
    qa1[1] = *(const short8*)&qh[(size_t)(qrow+64)*DK + 32 + kq];
  }
  short8 vones;
  #pragma unroll
  for (int j=0;j<8;j++) vones[j] = (short)0x3F80;

  f32x4 zero4 = {0.f,0.f,0.f,0.f};
  f32x4 o0[4], o1[4];
  float lr0 = 0.f, lr1 = 0.f;
  #pragma unroll
  for (int n=0;n<4;n++){ o0[n]=zero4; o1[n]=zero4; }

  gload_lds16(kg0 + (size_t)t0*4096, &Ksm[0][ld0]);
  gload_lds16(kg1 + (size_t)t0*4096, &Ksm[0][ld1]);
  gload_lds16(vg0 + (size_t)t0*64,   &Vsm[0][ld0]);
  gload_lds16(vg1 + (size_t)t0*64,   &Vsm[0][ld1]);

  int cur = 0;
  for (int t=t0; t<=t1; t++){
    if (t < t1){
      gload_lds16(kg0 + (size_t)(t+1)*4096, &Ksm[cur^1][ld0]);
      gload_lds16(kg1 + (size_t)(t+1)*4096, &Ksm[cur^1][ld1]);
      gload_lds16(vg0 + (size_t)(t+1)*64,   &Vsm[cur^1][ld0]);
      gload_lds16(vg1 + (size_t)(t+1)*64,   &Vsm[cur^1][ld1]);
      asm volatile("s_waitcnt vmcnt(4)" ::: "memory");
    } else {
      asm volatile("s_waitcnt vmcnt(0)" ::: "memory");
    }
    __builtin_amdgcn_s_barrier();
    asm volatile("" ::: "memory");

    f32x4 sa[4], sb[4];
    #pragma unroll
    for (int n=0;n<4;n++){ sa[n]=zero4; sb[n]=zero4; }
    #pragma unroll
    for (int n=0;n<4;n++)
      #pragma unroll
      for (int kk=0;kk<2;kk++){
        short8 kb = *(const short8*)&Ksm[cur][(((n*16 + r0)*64) + kk*32 + kq) ^ swr];
        sa[n] = __builtin_amdgcn_mfma_f32_16x16x32_bf16(kb, qa0[kk], sa[n], 0,0,0);
        sb[n] = __builtin_amdgcn_mfma_f32_16x16x32_bf16(kb, qa1[kk], sb[n], 0,0,0);
      }

    #pragma unroll
    for (int n=0;n<4;n++)
      #pragma unroll
      for (int reg=0;reg<4;reg++){
        sa[n][reg] = exp2f(sa[n][reg]);
        sb[n][reg] = exp2f(sb[n][reg]);
      }

    short8 pa0[2], pa1[2];
    #pragma unroll
    for (int kk=0;kk<2;kk++){
      u32x4 w0, w1;
      w0[0] = cvt_pk2(sa[2*kk][0],   sa[2*kk][1]);
      w0[1] = cvt_pk2(sa[2*kk][2],   sa[2*kk][3]);
      w0[2] = cvt_pk2(sa[2*kk+1][0], sa[2*kk+1][1]);
      w0[3] = cvt_pk2(sa[2*kk+1][2], sa[2*kk+1][3]);
      pa0[kk] = __builtin_bit_cast(short8, w0);
      w1[0] = cvt_pk2(sb[2*kk][0],   sb[2*kk][1]);
      w1[1] = cvt_pk2(sb[2*kk][2],   sb[2*kk][3]);
      w1[2] = cvt_pk2(sb[2*kk+1][0], sb[2*kk+1][1]);
      w1[3] = cvt_pk2(sb[2*kk+1][2], sb[2*kk+1][3]);
      pa1[kk] = __builtin_bit_cast(short8, w1);
    }

    {
      f32x4 ls = zero4;
      ls = __builtin_amdgcn_mfma_f32_16x16x32_bf16(vones, pa0[0], ls, 0,0,0);
      ls = __builtin_amdgcn_mfma_f32_16x16x32_bf16(vones, pa0[1], ls, 0,0,0);
      lr0 += ls[0];
      f32x4 ls2 = zero4;
      ls2 = __builtin_amdgcn_mfma_f32_16x16x32_bf16(vones, pa1[0], ls2, 0,0,0);
      ls2 = __builtin_amdgcn_mfma_f32_16x16x32_bf16(vones, pa1[1], ls2, 0,0,0);
      lr1 += ls2[0];
    }

    #pragma unroll
    for (int n=0;n<4;n++)
      #pragma unroll
      for (int kk=0;kk<2;kk++){
        short8 vb = *(const short8*)&Vsm[cur][(((n*16 + r0)*64) + kk*32 + cq*8) ^ swr];
        o0[n] = __builtin_amdgcn_mfma_f32_16x16x32_bf16(vb, pa0[kk], o0[n], 0,0,0);
        o1[n] = __builtin_amdgcn_mfma_f32_16x16x32_bf16(vb, pa1[kk], o1[n], 0,0,0);
      }

    asm volatile("" ::: "memory");
    __builtin_amdgcn_s_barrier();
    asm volatile("" ::: "memory");
    cur ^= 1;
  }

  unsigned short* pop = pob + (size_t)chunk*4194304;
  float* mlp = ml + (size_t)chunk*65536;
  const int bh = b*16 + h;
  const int rowA = (bh*16 + qB)*128 + wave*16 + r0;
  const int rowB = rowA + 64;
  if (cq == 0){ mlp[rowA] = lr0; mlp[rowB] = lr1; }
  #pragma unroll
  for (int n=0;n<4;n++){
    uint2 w0;
    w0.x = cvt_pk2(o0[n][0], o0[n][1]);
    w0.y = cvt_pk2(o0[n][2], o0[n][3]);
    *(uint2*)(pop + (size_t)rowA*64 + n*16 + cq*4) = w0;
    uint2 w1;
    w1.x = cvt_pk2(o1[n][0], o1[n][1]);
    w1.y = cvt_pk2(o1[n][2], o1[n][3]);
    *(uint2*)(pop + (size_t)rowB*64 + n*16 + cq*4) = w1;
  }
}

// ---------------- merge two causal (o,l) f32 partials (rows s in [1024,2048)) ----------------
__global__ __launch_bounds__(256) void attn_merge(
    const float* __restrict__ po, const float* __restrict__ ml,
    unsigned short* __restrict__ O)
{
  int gid = blockIdx.x*256 + threadIdx.x;
  int row = gid>>4, dq = (gid&15)*4;
  float l0 = ml[row], l1 = ml[32768 + row];
  float inv = 1.f / (l0 + l1);
  float4 v0 = *(const float4*)(po + (size_t)row*64 + dq);
  float4 v1 = *(const float4*)(po + 2097152 + (size_t)row*64 + dq);
  float r0 = (v0.x + v1.x)*inv;
  float r1 = (v0.y + v1.y)*inv;
  float r2 = (v0.z + v1.z)*inv;
  float r3 = (v0.w + v1.w)*inv;
  int bh = row>>10, qb16 = (row>>6)&15, qr = row&63;
  int b = bh>>4, h = bh&15;
  int s = (16+qb16)*64 + qr;
  unsigned short* op = O + ((size_t)b*2048 + s)*1024 + h*64 + dq;
  uint2 out; out.x = cvt_pk2(r0, r1); out.y = cvt_pk2(r2, r3);
  *(uint2*)op = out;
}

// ---------------- merge two cross bf16 (o) + f32 l partials (all rows) ----------------
__global__ __launch_bounds__(256) void attn_merge_x(
    const unsigned short* __restrict__ pob, const float* __restrict__ ml,
    unsigned short* __restrict__ O)
{
  int gid = blockIdx.x*256 + threadIdx.x;
  int row = gid>>4, dq = (gid&15)*4;
  float l0 = ml[row], l1 = ml[65536 + row];
  float inv = 1.f / (l0 + l1);
  ushort4 u0 = *(const ushort4*)(pob + (size_t)row*64 + dq);
  ushort4 u1 = *(const ushort4*)(pob + 4194304 + (size_t)row*64 + dq);
  float r0 = (b2f(u0.x) + b2f(u1.x))*inv;
  float r1 = (b2f(u0.y) + b2f(u1.y))*inv;
  float r2 = (b2f(u0.z) + b2f(u1.z))*inv;
  float r3 = (b2f(u0.w) + b2f(u1.w))*inv;
  int bh = row>>11, s = row&2047;
  int b = bh>>4, h = bh&15;
  unsigned short* op = O + ((size_t)b*2048 + s)*1024 + h*64 + dq;
  uint2 out; out.x = cvt_pk2(r0, r1); out.y = cvt_pk2(r2, r3);
  *(uint2*)op = out;
}

// ---------------- 5-way add + layernorm (4 GEMM partials + residual) ----------------
__global__ __launch_bounds__(256) void add_ln5(
    const unsigned short* __restrict__ a0, const unsigned short* __restrict__ a1,
    const unsigned short* __restrict__ a2, const unsigned short* __restrict__ a3,
    const unsigned short* __restrict__ r,
    const float* __restrict__ g, const float* __restrict__ be,
    unsigned short* __restrict__ outp)
{
  const int row = blockIdx.x, tid = threadIdx.x;
  const size_t base = (size_t)row*1024 + tid*4;
  ushort4 v0 = *(const ushort4*)(a0 + base);
  ushort4 v1 = *(const ushort4*)(a1 + base);
  ushort4 v2 = *(const ushort4*)(a2 + base);
  ushort4 v3 = *(const ushort4*)(a3 + base);
  ushort4 vr = *(const ushort4*)(r + base);
  float x[4];
  x[0] = b2f(v0.x)+b2f(v1.x)+b2f(v2.x)+b2f(v3.x)+b2f(vr.x);
  x[1] = b2f(v0.y)+b2f(v1.y)+b2f(v2.y)+b2f(v3.y)+b2f(vr.y);
  x[2] = b2f(v0.z)+b2f(v1.z)+b2f(v2.z)+b2f(v3.z)+b2f(vr.z);
  x[3] = b2f(v0.w)+b2f(v1.w)+b2f(v2.w)+b2f(v3.w)+b2f(vr.w);
  float s = x[0]+x[1]+x[2]+x[3];
  float ss = x[0]*x[0]+x[1]*x[1]+x[2]*x[2]+x[3]*x[3];
  #pragma unroll
  for (int d=1;d<64;d<<=1){ s += __shfl_xor(s,d,64); ss += __shfl_xor(ss,d,64); }
  __shared__ float rs[4], rss[4];
  int wave = tid>>6, lane = tid&63;
  if (lane==0){ rs[wave]=s; rss[wave]=ss; }
  __syncthreads();
  s = rs[0]+rs[1]+rs[2]+rs[3];
  ss = rss[0]+rss[1]+rss[2]+rss[3];
  float mean = s*(1.f/1024.f);
  float var = (ss - 1024.f*mean*mean)*(1.f/1023.f);
  float sd = sqrtf(fmaxf(var,0.f));
  float inv = 1.f/(sd + 1e-5f);
  float4 vg = *(const float4*)(g + tid*4);
  float4 vbe = *(const float4*)(be + tid*4);
  float o0 = (x[0]-mean)*inv*vg.x+vbe.x;
  float o1 = (x[1]-mean)*inv*vg.y+vbe.y;
  float o2 = (x[2]-mean)*inv*vg.z+vbe.z;
  float o3 = (x[3]-mean)*inv*vg.w+vbe.w;
  uint2 vo; vo.x = cvt_pk2(o0,o1); vo.y = cvt_pk2(o2,o3);
  *(uint2*)(outp + base) = vo;
}

// ---------------- 3-way add + layernorm (ddof=1, eps on std) ----------------
template<int OUT_F32>
__global__ __launch_bounds__(256) void add_ln3(
    const unsigned short* __restrict__ a0, const unsigned short* __restrict__ a1,
    const unsigned short* __restrict__ r,
    const float* __restrict__ g, const float* __restrict__ be, void* outp)
{
  const int row = blockIdx.x, tid = threadIdx.x;
  const size_t base = (size_t)row*1024 + tid*4;
  ushort4 va = *(const ushort4*)(a0 + base);
  ushort4 vb_ = *(const ushort4*)(a1 + base);
  ushort4 vr = *(const ushort4*)(r + base);
  float x[4];
  x[0] = b2f(va.x)+b2f(vb_.x)+b2f(vr.x);
  x[1] = b2f(va.y)+b2f(vb_.y)+b2f(vr.y);
  x[2] = b2f(va.z)+b2f(vb_.z)+b2f(vr.z);
  x[3] = b2f(va.w)+b2f(vb_.w)+b2f(vr.w);
  float s = x[0]+x[1]+x[2]+x[3];
  float ss = x[0]*x[0]+x[1]*x[1]+x[2]*x[2]+x[3]*x[3];
  #pragma unroll
  for (int d=1;d<64;d<<=1){ s += __shfl_xor(s,d,64); ss += __shfl_xor(ss,d,64); }
  __shared__ float rs[4], rss[4];
  int wave = tid>>6, lane = tid&63;
  if (lane==0){ rs[wave]=s; rss[wave]=ss; }
  __syncthreads();
  s = rs[0]+rs[1]+rs[2]+rs[3];
  ss = rss[0]+rss[1]+rss[2]+rss[3];
  float mean = s*(1.f/1024.f);
  float var = (ss - 1024.f*mean*mean)*(1.f/1023.f);
  float sd = sqrtf(fmaxf(var,0.f));
  float inv = 1.f/(sd + 1e-5f);
  float4 vg = *(const float4*)(g + tid*4);
  float4 vbe = *(const float4*)(be + tid*4);
  float o0 = (x[0]-mean)*inv*vg.x+vbe.x;
  float o1 = (x[1]-mean)*inv*vg.y+vbe.y;
  float o2 = (x[2]-mean)*inv*vg.z+vbe.z;
  float o3 = (x[3]-mean)*inv*vg.w+vbe.w;
  if (OUT_F32){
    float4 vo; vo.x=o0; vo.y=o1; vo.z=o2; vo.w=o3;
    *(float4*)((float*)outp + base) = vo;
  } else {
    uint2 vo; vo.x = cvt_pk2(o0,o1); vo.y = cvt_pk2(o2,o3);
    *(uint2*)((unsigned short*)outp + base) = vo;
  }
}

extern "C" void kernel_launch(void* const* d_in, const int* in_sizes, int n_in,
                              void* d_out, int out_size, void* d_ws, size_t ws_size,
                              hipStream_t stream)
{
  typedef const float* cf;
  cf X   = (cf)d_in[0],  y   = (cf)d_in[1];
  cf wq1 = (cf)d_in[2],  bq1 = (cf)d_in[3],  wk1 = (cf)d_in[4],  bk1 = (cf)d_in[5];
  cf wv1 = (cf)d_in[6],  bv1 = (cf)d_in[7],  wo1 = (cf)d_in[8],  bo1 = (cf)d_in[9];
  cf wq2 = (cf)d_in[10], bq2 = (cf)d_in[11], wk2 = (cf)d_in[12], bk2 = (cf)d_in[13];
  cf wv2 = (cf)d_in[14], bv2 = (cf)d_in[15], wo2 = (cf)d_in[16], bo2 = (cf)d_in[17];
  cf wf1 = (cf)d_in[18], bf1 = (cf)d_in[19], wf2 = (cf)d_in[20], bf2 = (cf)d_in[21];
  cf g1  = (cf)d_in[22], be1 = (cf)d_in[23], g2  = (cf)d_in[24], be2 = (cf)d_in[25];
  cf g3  = (cf)d_in[26], be3 = (cf)d_in[27];

  char* ws = (char*)d_ws;
  const size_t MB = 1u<<20;
  unsigned short* wq1t = (unsigned short*)(ws + 0*MB);
  unsigned short* wk1t = (unsigned short*)(ws + 2*MB);
  unsigned short* wv1t = (unsigned short*)(ws + 4*MB);
  unsigned short* wo1t = (unsigned short*)(ws + 6*MB);
  unsigned short* wq2t = (unsigned short*)(ws + 8*MB);
  unsigned short* wk2t = (unsigned short*)(ws + 10*MB);
  unsigned short* wv2t = (unsigned short*)(ws + 12*MB);
  unsigned short* wo2t = (unsigned short*)(ws + 14*MB);
  unsigned short* wf1t = (unsigned short*)(ws + 16*MB);
  unsigned short* wf2t = (unsigned short*)(ws + 24*MB);
  unsigned short* Qb   = (unsigned short*)(ws + 32*MB);
  unsigned short* Kb   = (unsigned short*)(ws + 40*MB);
  unsigned short* Vtb  = (unsigned short*)(ws + 48*MB);
  unsigned short* attno= (unsigned short*)(ws + 56*MB);
  unsigned short* hbuf = (unsigned short*)(ws + 32*MB);   // stage C only (32-64MB)
  unsigned short* part = (unsigned short*)(ws + 64*MB);   // GEMM partials 0,1 (2x8MB)
  unsigned short* part23 = (unsigned short*)(ws + 32*MB); // GEMM partials 2,3 (over dead Qb/Kb)
  float*          poF  = (float*)(ws + 64*MB);            // causal f32 partials (2x8MB)
  unsigned short* pobF = (unsigned short*)(ws + 64*MB);   // cross bf16 partials (2x8MB)
  float*          mlF  = (float*)(ws + 80*MB);            // causal l (256KB)
  unsigned short* x1b  = (unsigned short*)(ws + 80*MB);   // overwrites mlF after merge
  unsigned short* slot = (unsigned short*)(ws + 88*MB);   // yb -> Xb -> (mlX / x2b)
  unsigned short* yb = slot, *Xb = slot, *x2b = slot;
  float*          mlX  = (float*)(ws + 88*MB);            // cross l (512KB, over dead Xb)

  dim3 blk(256);
  const int NTOK = 2*2048*1024;
  cvt_f32_bf16<<<NTOK/1024, blk, 0, stream>>>(y, yb, NTOK);

  {
    TransAll tp;
    const float* Ws[10]   = {wq1,wk1,wv1,wo1,wq2,wk2,wv2,wo2,wf1,wf2};
    unsigned short* Ts[10]= {wq1t,wk1t,wv1t,wo1t,wq2t,wk2t,wv2t,wo2t,wf1t,wf2t};
    for (int i=0;i<10;i++){
      tp.W[i]=Ws[i]; tp.Wt[i]=Ts[i];
      tp.K[i] = (i==9)?4096:1024;
      tp.N[i] = (i==8)?4096:1024;
      tp.swapxy[i] = (i==9)?1:0;
    }
    transpose_cvt_all<<<dim3(128,32,10), blk, 0, stream>>>(tp);
  }

  dim3 gqkv(24,32);        // fused QKV 128^2: 768 blocks
  dim3 gs4(8,32,4);        // O-proj split-K4 128^2: 1024 blocks
  dim3 gs2(8,32,2);        // FFN2 split-K2: 512 blocks
  dim3 gff1(32,32,1);      // FFN1 128^2: 1024 blocks
  dim3 gac(48,16,2);       // causal attn split: 1536 blocks (QB=64)
  dim3 gax(32,16,2);       // cross attn QB=128 split-K2: 1024 blocks

  // ---- stage A: causal self-attention on y ----
  {
    QKVArgs a1;
    a1.Aw[0]=yb; a1.Aw[1]=yb; a1.Aw[2]=yb;
    a1.bias[0]=bq1; a1.bias[1]=bk1; a1.bias[2]=bv1;
    a1.out[0]=Qb; a1.out[1]=Kb; a1.out[2]=Vtb;
    gemm_qkv<<<gqkv, blk, 0, stream>>>(wq1t, a1, 4096, 1024);
  }
  attn_causal<<<gac, blk, 0, stream>>>(Qb, Kb, Vtb, attno, poF, mlF);
  attn_merge<<<2048, blk, 0, stream>>>(poF, mlF, attno);
  // O-proj split-K4: partials 0,1 over dead poF; 2,3 over dead Qb/Kb
  gemm_bt<0><<<gs4, blk, 0, stream>>>(attno, wo1t, bo1, part, part23, 4096, 1024, 256, 1024, 1024);
  add_ln5<<<4096, blk, 0, stream>>>(part, part+4194304, part23, part23+4194304, yb, g1, be1, x1b);

  // ---- stage B: cross-attention (Q from x1b, K/V from X) ----
  cvt_f32_bf16<<<NTOK/1024, blk, 0, stream>>>(X, Xb, NTOK);
  {
    QKVArgs a2;
    a2.Aw[0]=x1b; a2.Aw[1]=Xb; a2.Aw[2]=Xb;
    a2.bias[0]=bq2; a2.bias[1]=bk2; a2.bias[2]=bv2;
    a2.out[0]=Qb; a2.out[1]=Kb; a2.out[2]=Vtb;
    gemm_qkv<<<gqkv, blk, 0, stream>>>(wq2t, a2, 4096, 1024);
  }
  attn_cross2<<<gax, blk, 0, stream>>>(Qb, Kb, Vtb, pobF, mlX);
  attn_merge_x<<<4096, blk, 0, stream>>>(pobF, mlX, attno);
  gemm_bt<0><<<gs4, blk, 0, stream>>>(attno, wo2t, bo2, part, part23, 4096, 1024, 256, 1024, 1024);
  add_ln5<<<4096, blk, 0, stream>>>(part, part+4194304, part23, part23+4194304, x1b, g2, be2, x2b);

  // ---- stage C: FFN ----
  gemm_bt<1><<<gff1, blk, 0, stream>>>(x2b, wf1t, bf1, hbuf, (unsigned short*)nullptr, 4096, 4096, 1024, 1024, 1024);
  gemm_bt<0><<<gs2, blk, 0, stream>>>(hbuf, wf2t, bf2, part, (unsigned short*)nullptr, 4096, 1024, 2048, 4096, 4096);
  add_ln3<1><<<4096, blk, 0, stream>>>(part, part+4194304, x2b, g3, be3, d_out);
}

// Round 26
// 380.960 us; speedup vs baseline: 1.0270x; 1.0270x over previous
//
#include <hip/hip_runtime.h>

#define DEV __device__ __forceinline__

typedef __attribute__((ext_vector_type(8))) short short8;
typedef __attribute__((ext_vector_type(4))) float f32x4;
typedef __attribute__((ext_vector_type(4))) unsigned u32x4;

DEV unsigned short f2b(float f){
  unsigned r;
  asm("v_cvt_pk_bf16_f32 %0, %1, %1" : "=v"(r) : "v"(f));
  return (unsigned short)r;
}
DEV unsigned cvt_pk2(float lo, float hi){
  unsigned r;
  asm("v_cvt_pk_bf16_f32 %0, %1, %2" : "=v"(r) : "v"(lo), "v"(hi));
  return r;
}
DEV float b2f(unsigned short u){ unsigned v = ((unsigned)u)<<16; float f; __builtin_memcpy(&f,&v,4); return f; }

DEV void gload_lds16(const void* g, void* l){
  __builtin_amdgcn_global_load_lds((const __attribute__((address_space(1))) void*)g,
                                   (__attribute__((address_space(3))) void*)l, 16, 0, 0);
}

#define SCL 0.18033688011112042f   /* 0.125 * log2(e) */

// ---------------- f32 -> bf16 elementwise ----------------
__global__ __launch_bounds__(256) void cvt_f32_bf16(
    const float* __restrict__ in, unsigned short* __restrict__ out, int n)
{
  int i = (blockIdx.x*256 + threadIdx.x)*4;
  if (i >= n) return;
  float4 v = *(const float4*)(in + i);
  uint2 o;
  o.x = cvt_pk2(v.x, v.y);
  o.y = cvt_pk2(v.z, v.w);
  *(uint2*)(out + i) = o;
}

// ---------------- batched transpose+convert: Wt[n*K+k] = bf16(W[k*N+n]) ----------------
struct TransAll {
  const float* W[10]; unsigned short* Wt[10];
  int K[10], N[10], swapxy[10];
};
__global__ __launch_bounds__(256) void transpose_cvt_all(TransAll p)
{
  const int z = blockIdx.z;
  const int bx = p.swapxy[z] ? blockIdx.y : blockIdx.x;
  const int by = p.swapxy[z] ? blockIdx.x : blockIdx.y;
  const int K = p.K[z], N = p.N[z];
  const int n0 = bx*32, k0 = by*32;
  if (n0 >= N || k0 >= K) return;
  const float* __restrict__ W = p.W[z];
  unsigned short* __restrict__ Wt = p.Wt[z];
  __shared__ float tile[32][33];
  int tx = threadIdx.x & 31, ty = threadIdx.x >> 5;
  #pragma unroll
  for (int j=0;j<32;j+=8)
    tile[ty+j][tx] = W[(size_t)(k0+ty+j)*N + n0+tx];
  __syncthreads();
  #pragma unroll
  for (int j=0;j<32;j+=8)
    Wt[(size_t)(n0+ty+j)*K + k0+tx] = f2b(tile[tx][ty+j]);
}

// ---------------- GEMM 128x128, BK=64, swizzled LDS (conflict-free reads) ----------------
template<int EPI>
__global__ __launch_bounds__(256) void gemm_bt(
    const unsigned short* __restrict__ A,
    const unsigned short* __restrict__ Bt,
    const float* __restrict__ bias,
    unsigned short* __restrict__ C,
    int M, int N, int Kc, int LDA, int LDB)
{
  __shared__ alignas(16) unsigned short Asm_[128*64];
  __shared__ alignas(16) unsigned short Bsm_[128*64];
  const int tid = threadIdx.x;
  const int wave = tid>>6, lane = tid&63;
  const int r0 = lane&15, kq = (lane>>4)*8, cq = lane>>4;
  const int m0 = blockIdx.y*128, n0 = blockIdx.x*128;
  const int wr = wave>>1, wc = wave&1;
  const int koff = blockIdx.z * Kc;
  const bool addb = (blockIdx.z == 0);
  C += (size_t)blockIdx.z * M * N;
  const int swr = (r0&7)<<3;

  f32x4 zero4 = {0.f,0.f,0.f,0.f};
  f32x4 acc[4][4];
  #pragma unroll
  for (int m=0;m<4;m++)
    #pragma unroll
    for (int n=0;n<4;n++) acc[m][n]=zero4;

  const int nk = Kc>>6;
  for (int kt=0; kt<nk; kt++){
    #pragma unroll
    for (int i=0;i<4;i++){
      int idx = i*256 + tid;
      int row = idx>>3;
      int sc = ((idx&7) ^ (row&7))<<3;
      gload_lds16(A  + (size_t)(m0+row)*LDA + koff + (kt<<6) + sc, Asm_ + (size_t)idx*8);
      gload_lds16(Bt + (size_t)(n0+row)*LDB + koff + (kt<<6) + sc, Bsm_ + (size_t)idx*8);
    }
    __syncthreads();
    #pragma unroll
    for (int kk=0;kk<2;kk++){
      short8 a[4], b[4];
      #pragma unroll
      for (int m=0;m<4;m++)
        a[m] = *(const short8*)&Asm_[(((wr*64 + m*16 + r0)*64) + kk*32 + kq) ^ swr];
      #pragma unroll
      for (int n=0;n<4;n++)
        b[n] = *(const short8*)&Bsm_[(((wc*64 + n*16 + r0)*64) + kk*32 + kq) ^ swr];
      #pragma unroll
      for (int m=0;m<4;m++)
        #pragma unroll
        for (int n=0;n<4;n++)
          acc[m][n] = __builtin_amdgcn_mfma_f32_16x16x32_bf16(a[m], b[n], acc[m][n], 0,0,0);
    }
    __syncthreads();
  }

  #pragma unroll
  for (int n=0;n<4;n++){
    int col = n0 + wc*64 + n*16 + r0;
    float bs = addb ? bias[col] : 0.f;
    #pragma unroll
    for (int m=0;m<4;m++){
      int rowb = m0 + wr*64 + m*16 + cq*4;
      #pragma unroll
      for (int reg=0;reg<4;reg++){
        float v = acc[m][n][reg] + bs;
        if (EPI==1) v = fmaxf(v, 0.f);
        C[(size_t)(rowb+reg)*N + col] = f2b(v);
      }
    }
  }
}

// ---------------- fused QKV GEMM (128x128, BK=64, swizzled; N=3072, per-which A) ----------------
struct QKVArgs { const unsigned short* Aw[3]; const float* bias[3]; unsigned short* out[3]; };
__global__ __launch_bounds__(256) void gemm_qkv(
    const unsigned short* __restrict__ Bt,
    QKVArgs args, int M, int K)
{
  __shared__ alignas(16) unsigned short Asm_[128*64];
  __shared__ alignas(16) unsigned short Bsm_[128*64];
  const int tid = threadIdx.x;
  const int wave = tid>>6, lane = tid&63;
  const int r0 = lane&15, kq = (lane>>4)*8, cq = lane>>4;
  const int m0 = blockIdx.y*128, n0 = blockIdx.x*128;
  const int wr = wave>>1, wc = wave&1;
  const int which = n0>>10;
  const unsigned short* __restrict__ A = args.Aw[which];
  const int swr = (r0&7)<<3;

  f32x4 zero4 = {0.f,0.f,0.f,0.f};
  f32x4 acc[4][4];
  #pragma unroll
  for (int m=0;m<4;m++)
    #pragma unroll
    for (int n=0;n<4;n++) acc[m][n]=zero4;

  const int nk = K>>6;
  for (int kt=0; kt<nk; kt++){
    #pragma unroll
    for (int i=0;i<4;i++){
      int idx = i*256 + tid;
      int row = idx>>3;
      int sc = ((idx&7) ^ (row&7))<<3;
      gload_lds16(A  + (size_t)(m0+row)*K + (kt<<6) + sc, Asm_ + (size_t)idx*8);
      gload_lds16(Bt + (size_t)(n0+row)*K + (kt<<6) + sc, Bsm_ + (size_t)idx*8);
    }
    __syncthreads();
    #pragma unroll
    for (int kk=0;kk<2;kk++){
      short8 a[4], b[4];
      #pragma unroll
      for (int m=0;m<4;m++)
        a[m] = *(const short8*)&Asm_[(((wr*64 + m*16 + r0)*64) + kk*32 + kq) ^ swr];
      #pragma unroll
      for (int n=0;n<4;n++)
        b[n] = *(const short8*)&Bsm_[(((wc*64 + n*16 + r0)*64) + kk*32 + kq) ^ swr];
      #pragma unroll
      for (int m=0;m<4;m++)
        #pragma unroll
        for (int n=0;n<4;n++)
          acc[m][n] = __builtin_amdgcn_mfma_f32_16x16x32_bf16(a[m], b[n], acc[m][n], 0,0,0);
    }
    __syncthreads();
  }

  const int n0l = n0 & 1023;
  unsigned short* __restrict__ Cout = args.out[which];
  const float* __restrict__ bp = args.bias[which];
  const bool isV = (which == 2);
  const float scl = (which == 0) ? SCL : 1.f;

  #pragma unroll
  for (int n=0;n<4;n++){
    int col = n0l + wc*64 + n*16 + r0;
    float bs = bp[col];
    int h_ = col>>6, dk = col&63;
    #pragma unroll
    for (int m=0;m<4;m++){
      int rowb = m0 + wr*64 + m*16 + cq*4;
      #pragma unroll
      for (int reg=0;reg<4;reg++){
        float v = (acc[m][n][reg] + bs) * scl;
        int row = rowb + reg;
        int b_ = row>>11, s_ = row&2047;
        if (isV){
          int sp = (s_ & ~31) | (((s_>>2)&3)<<3) | (((s_>>4)&1)<<2) | (s_&3);
          Cout[(((size_t)(b_*16+h_))*64 + dk)*2048 + sp] = f2b(v);
        } else {
          Cout[(((size_t)(b_*16+h_))*2048 + s_)*64 + dk] = f2b(v);
        }
      }
    }
  }
}

// ---------------- causal flash attention (QB=64, proven) ----------------
__global__ __launch_bounds__(256, 4) void attn_causal(
    const unsigned short* __restrict__ Q,
    const unsigned short* __restrict__ K,
    const unsigned short* __restrict__ Vt,
    unsigned short* __restrict__ O,
    float* __restrict__ po, float* __restrict__ ml)
{
  __shared__ alignas(16) unsigned short Ksm[2][64*64];
  __shared__ alignas(16) unsigned short Vsm[2][64*64];
  const int S = 2048, DK = 64;
  const int h = blockIdx.y, b = blockIdx.z;
  const int tid = threadIdx.x, wave = tid>>6, lane = tid&63;
  const int r0 = lane&15, kq = (lane>>4)*8, cq = lane>>4;

  int qb, t0, t1, chunk = 0;
  bool partial = false;
  {
    int bx = blockIdx.x;
    if (bx < 32){ qb = bx; t0 = 0; t1 = (qb<15?qb:15); chunk = 0; partial = (qb>=16); }
    else        { qb = bx-16; t0 = 16; t1 = qb; chunk = 1; partial = true; }
  }

  const unsigned short* qh = Q  + ((size_t)(b*16+h))*S*DK;
  const unsigned short* kh = K  + ((size_t)(b*16+h))*S*DK;
  const unsigned short* vh = Vt + ((size_t)(b*16+h))*DK*S;

  const int idx0 = tid, idx1 = 256 + tid;
  const int row0 = idx0>>3, row1 = idx1>>3;
  const int cb0 = ((idx0&7) ^ (row0&7))<<3;
  const int cb1 = ((idx1&7) ^ (row1&7))<<3;
  const unsigned short* kg0 = kh + (size_t)row0*64 + cb0;
  const unsigned short* kg1 = kh + (size_t)row1*64 + cb1;
  const unsigned short* vg0 = vh + (size_t)row0*2048 + cb0;
  const unsigned short* vg1 = vh + (size_t)row1*2048 + cb1;
  const int ld0 = wave*512, ld1 = 2048 + wave*512;
  const int swr = (r0&7)<<3;

  short8 qa[2];
  {
    int qrow = qb*64 + wave*16 + r0;
    qa[0] = *(const short8*)&qh[(size_t)qrow*DK + kq];
    qa[1] = *(const short8*)&qh[(size_t)qrow*DK + 32 + kq];
  }
  short8 vones;
  #pragma unroll
  for (int j=0;j<8;j++) vones[j] = (short)0x3F80;

  f32x4 zero4 = {0.f,0.f,0.f,0.f};
  f32x4 o[4];
  float lr = 0.f;
  #pragma unroll
  for (int n=0;n<4;n++) o[n]=zero4;

  gload_lds16(kg0 + (size_t)t0*4096, &Ksm[0][ld0]);
  gload_lds16(kg1 + (size_t)t0*4096, &Ksm[0][ld1]);
  gload_lds16(vg0 + (size_t)t0*64,   &Vsm[0][ld0]);
  gload_lds16(vg1 + (size_t)t0*64,   &Vsm[0][ld1]);

  int cur = 0;
  for (int t=t0; t<=t1; t++){
    if (t < t1){
      gload_lds16(kg0 + (size_t)(t+1)*4096, &Ksm[cur^1][ld0]);
      gload_lds16(kg1 + (size_t)(t+1)*4096, &Ksm[cur^1][ld1]);
      gload_lds16(vg0 + (size_t)(t+1)*64,   &Vsm[cur^1][ld0]);
      gload_lds16(vg1 + (size_t)(t+1)*64,   &Vsm[cur^1][ld1]);
      asm volatile("s_waitcnt vmcnt(4)" ::: "memory");
    } else {
      asm volatile("s_waitcnt vmcnt(0)" ::: "memory");
    }
    __builtin_amdgcn_s_barrier();
    asm volatile("" ::: "memory");

    f32x4 sv[4];
    #pragma unroll
    for (int n=0;n<4;n++) sv[n]=zero4;
    #pragma unroll
    for (int n=0;n<4;n++)
      #pragma unroll
      for (int kk=0;kk<2;kk++){
        short8 kb = *(const short8*)&Ksm[cur][(((n*16 + r0)*64) + kk*32 + kq) ^ swr];
        sv[n] = __builtin_amdgcn_mfma_f32_16x16x32_bf16(kb, qa[kk], sv[n], 0,0,0);
      }
    if (t==qb){
      const int qg = wave*16 + r0;
      #pragma unroll
      for (int n=0;n<4;n++)
        #pragma unroll
        for (int reg=0;reg<4;reg++){
          if (n*16 + cq*4 + reg > qg) sv[n][reg] += -1000000000.0f;
        }
    }

    #pragma unroll
    for (int n=0;n<4;n++)
      #pragma unroll
      for (int reg=0;reg<4;reg++)
        sv[n][reg] = exp2f(sv[n][reg]);

    short8 pa[2];
    #pragma unroll
    for (int kk=0;kk<2;kk++){
      u32x4 w;
      w[0] = cvt_pk2(sv[2*kk][0],   sv[2*kk][1]);
      w[1] = cvt_pk2(sv[2*kk][2],   sv[2*kk][3]);
      w[2] = cvt_pk2(sv[2*kk+1][0], sv[2*kk+1][1]);
      w[3] = cvt_pk2(sv[2*kk+1][2], sv[2*kk+1][3]);
      pa[kk] = __builtin_bit_cast(short8, w);
    }

    {
      f32x4 ls = zero4;
      ls = __builtin_amdgcn_mfma_f32_16x16x32_bf16(vones, pa[0], ls, 0,0,0);
      ls = __builtin_amdgcn_mfma_f32_16x16x32_bf16(vones, pa[1], ls, 0,0,0);
      lr += ls[0];
    }

    #pragma unroll
    for (int n=0;n<4;n++)
      #pragma unroll
      for (int kk=0;kk<2;kk++){
        short8 vb = *(const short8*)&Vsm[cur][(((n*16 + r0)*64) + kk*32 + cq*8) ^ swr];
        o[n] = __builtin_amdgcn_mfma_f32_16x16x32_bf16(vb, pa[kk], o[n], 0,0,0);
      }

    asm volatile("" ::: "memory");
    __builtin_amdgcn_s_barrier();
    asm volatile("" ::: "memory");
    cur ^= 1;
  }

  if (partial){
    float* pop = po + (size_t)chunk*2097152;
    float* mlp = ml + (size_t)chunk*32768;
    const int bh = b*16 + h, qb16 = qb - 16;
    const int rowIdx = (bh*16 + qb16)*64 + wave*16 + r0;
    if (cq == 0) mlp[rowIdx] = lr;
    #pragma unroll
    for (int n=0;n<4;n++){
      float4 v; v.x=o[n][0]; v.y=o[n][1]; v.z=o[n][2]; v.w=o[n][3];
      *(float4*)&pop[(size_t)rowIdx*64 + n*16 + cq*4] = v;
    }
  } else {
    const int sg = qb*64 + wave*16 + r0;
    const float inv = 1.f / lr;
    unsigned short* op = O + ((size_t)b*S + sg)*1024 + h*64;
    #pragma unroll
    for (int n=0;n<4;n++){
      uint2 w;
      w.x = cvt_pk2(o[n][0]*inv, o[n][1]*inv);
      w.y = cvt_pk2(o[n][2]*inv, o[n][3]*inv);
      *(uint2*)(op + n*16 + cq*4) = w;
    }
  }
}

// ---------------- cross attention: QB=128 (2 q-subtiles share staged K/V) ----------------
__global__ __launch_bounds__(256, 2) void attn_cross2(
    const unsigned short* __restrict__ Q,
    const unsigned short* __restrict__ K,
    const unsigned short* __restrict__ Vt,
    unsigned short* __restrict__ pob,
    float* __restrict__ ml)
{
  __shared__ alignas(16) unsigned short Ksm[2][64*64];
  __shared__ alignas(16) unsigned short Vsm[2][64*64];
  const int S = 2048, DK = 64;
  const int h = blockIdx.y, b = blockIdx.z;
  const int tid = threadIdx.x, wave = tid>>6, lane = tid&63;
  const int r0 = lane&15, kq = (lane>>4)*8, cq = lane>>4;

  int qB, t0, t1, chunk;
  {
    int bx = blockIdx.x;
    if (bx < 16){ qB = bx; t0 = 0; t1 = 15; chunk = 0; }
    else        { qB = bx-16; t0 = 16; t1 = 31; chunk = 1; }
  }

  const unsigned short* qh = Q  + ((size_t)(b*16+h))*S*DK;
  const unsigned short* kh = K  + ((size_t)(b*16+h))*S*DK;
  const unsigned short* vh = Vt + ((size_t)(b*16+h))*DK*S;

  const int idx0 = tid, idx1 = 256 + tid;
  const int row0 = idx0>>3, row1 = idx1>>3;
  const int cb0 = ((idx0&7) ^ (row0&7))<<3;
  const int cb1 = ((idx1&7) ^ (row1&7))<<3;
  const unsigned short* kg0 = kh + (size_t)row0*64 + cb0;
  const unsigned short* kg1 = kh + (size_t)row1*64 + cb1;
  const unsigned short* vg0 = vh + (size_t)row0*2048 + cb0;
  const unsigned short* vg1 = vh + (size_t)row1*2048 + cb1;
  const int ld0 = wave*512, ld1 = 2048 + wave*512;
  const int swr = (r0&7)<<3;

  short8 qa0[2], qa1[2];
  {
    int qrow = qB*128 + wave*16 + r0;
    qa0[0] = *(const short8*)&qh[(size_t)qrow*DK + kq];
    qa0[1] = *(const short8*)&qh[(size_t)qrow*DK + 32 + kq];
    qa1[0] = *(const short8*)&qh[(size_t)(qrow+64)*DK + kq];
    qa1[1] = *(const short8*)&qh[(size_t)(qrow+64)*DK + 32 + kq];
  }
  short8 vones;
  #pragma unroll
  for (int j=0;j<8;j++) vones[j] = (short)0x3F80;

  f32x4 zero4 = {0.f,0.f,0.f,0.f};
  f32x4 o0[4], o1[4];
  float lr0 = 0.f, lr1 = 0.f;
  #pragma unroll
  for (int n=0;n<4;n++){ o0[n]=zero4; o1[n]=zero4; }

  gload_lds16(kg0 + (size_t)t0*4096, &Ksm[0][ld0]);
  gload_lds16(kg1 + (size_t)t0*4096, &Ksm[0][ld1]);
  gload_lds16(vg0 + (size_t)t0*64,   &Vsm[0][ld0]);
  gload_lds16(vg1 + (size_t)t0*64,   &Vsm[0][ld1]);

  int cur = 0;
  for (int t=t0; t<=t1; t++){
    if (t < t1){
      gload_lds16(kg0 + (size_t)(t+1)*4096, &Ksm[cur^1][ld0]);
      gload_lds16(kg1 + (size_t)(t+1)*4096, &Ksm[cur^1][ld1]);
      gload_lds16(vg0 + (size_t)(t+1)*64,   &Vsm[cur^1][ld0]);
      gload_lds16(vg1 + (size_t)(t+1)*64,   &Vsm[cur^1][ld1]);
      asm volatile("s_waitcnt vmcnt(4)" ::: "memory");
    } else {
      asm volatile("s_waitcnt vmcnt(0)" ::: "memory");
    }
    __builtin_amdgcn_s_barrier();
    asm volatile("" ::: "memory");

    f32x4 sa[4], sb[4];
    #pragma unroll
    for (int n=0;n<4;n++){ sa[n]=zero4; sb[n]=zero4; }
    #pragma unroll
    for (int n=0;n<4;n++)
      #pragma unroll
      for (int kk=0;kk<2;kk++){
        short8 kb = *(const short8*)&Ksm[cur][(((n*16 + r0)*64) + kk*32 + kq) ^ swr];
        sa[n] = __builtin_amdgcn_mfma_f32_16x16x32_bf16(kb, qa0[kk], sa[n], 0,0,0);
        sb[n] = __builtin_amdgcn_mfma_f32_16x16x32_bf16(kb, qa1[kk], sb[n], 0,0,0);
      }

    #pragma unroll
    for (int n=0;n<4;n++)
      #pragma unroll
      for (int reg=0;reg<4;reg++){
        sa[n][reg] = exp2f(sa[n][reg]);
        sb[n][reg] = exp2f(sb[n][reg]);
      }

    short8 pa0[2], pa1[2];
    #pragma unroll
    for (int kk=0;kk<2;kk++){
      u32x4 w0, w1;
      w0[0] = cvt_pk2(sa[2*kk][0],   sa[2*kk][1]);
      w0[1] = cvt_pk2(sa[2*kk][2],   sa[2*kk][3]);
      w0[2] = cvt_pk2(sa[2*kk+1][0], sa[2*kk+1][1]);
      w0[3] = cvt_pk2(sa[2*kk+1][2], sa[2*kk+1][3]);
      pa0[kk] = __builtin_bit_cast(short8, w0);
      w1[0] = cvt_pk2(sb[2*kk][0],   sb[2*kk][1]);
      w1[1] = cvt_pk2(sb[2*kk][2],   sb[2*kk][3]);
      w1[2] = cvt_pk2(sb[2*kk+1][0], sb[2*kk+1][1]);
      w1[3] = cvt_pk2(sb[2*kk+1][2], sb[2*kk+1][3]);
      pa1[kk] = __builtin_bit_cast(short8, w1);
    }

    {
      f32x4 ls = zero4;
      ls = __builtin_amdgcn_mfma_f32_16x16x32_bf16(vones, pa0[0], ls, 0,0,0);
      ls = __builtin_amdgcn_mfma_f32_16x16x32_bf16(vones, pa0[1], ls, 0,0,0);
      lr0 += ls[0];
      f32x4 ls2 = zero4;
      ls2 = __builtin_amdgcn_mfma_f32_16x16x32_bf16(vones, pa1[0], ls2, 0,0,0);
      ls2 = __builtin_amdgcn_mfma_f32_16x16x32_bf16(vones, pa1[1], ls2, 0,0,0);
      lr1 += ls2[0];
    }

    #pragma unroll
    for (int n=0;n<4;n++)
      #pragma unroll
      for (int kk=0;kk<2;kk++){
        short8 vb = *(const short8*)&Vsm[cur][(((n*16 + r0)*64) + kk*32 + cq*8) ^ swr];
        o0[n] = __builtin_amdgcn_mfma_f32_16x16x32_bf16(vb, pa0[kk], o0[n], 0,0,0);
        o1[n] = __builtin_amdgcn_mfma_f32_16x16x32_bf16(vb, pa1[kk], o1[n], 0,0,0);
      }

    asm volatile("" ::: "memory");
    __builtin_amdgcn_s_barrier();
    asm volatile("" ::: "memory");
    cur ^= 1;
  }

  unsigned short* pop = pob + (size_t)chunk*4194304;
  float* mlp = ml + (size_t)chunk*65536;
  const int bh = b*16 + h;
  const int rowA = (bh*16 + qB)*128 + wave*16 + r0;
  const int rowB = rowA + 64;
  if (cq == 0){ mlp[rowA] = lr0; mlp[rowB] = lr1; }
  #pragma unroll
  for (int n=0;n<4;n++){
    uint2 w0;
    w0.x = cvt_pk2(o0[n][0], o0[n][1]);
    w0.y = cvt_pk2(o0[n][2], o0[n][3]);
    *(uint2*)(pop + (size_t)rowA*64 + n*16 + cq*4) = w0;
    uint2 w1;
    w1.x = cvt_pk2(o1[n][0], o1[n][1]);
    w1.y = cvt_pk2(o1[n][2], o1[n][3]);
    *(uint2*)(pop + (size_t)rowB*64 + n*16 + cq*4) = w1;
  }
}

// ---------------- merge two causal (o,l) f32 partials (rows s in [1024,2048)) ----------------
__global__ __launch_bounds__(256) void attn_merge(
    const float* __restrict__ po, const float* __restrict__ ml,
    unsigned short* __restrict__ O)
{
  int gid = blockIdx.x*256 + threadIdx.x;
  int row = gid>>4, dq = (gid&15)*4;
  float l0 = ml[row], l1 = ml[32768 + row];
  float inv = 1.f / (l0 + l1);
  float4 v0 = *(const float4*)(po + (size_t)row*64 + dq);
  float4 v1 = *(const float4*)(po + 2097152 + (size_t)row*64 + dq);
  float r0 = (v0.x + v1.x)*inv;
  float r1 = (v0.y + v1.y)*inv;
  float r2 = (v0.z + v1.z)*inv;
  float r3 = (v0.w + v1.w)*inv;
  int bh = row>>10, qb16 = (row>>6)&15, qr = row&63;
  int b = bh>>4, h = bh&15;
  int s = (16+qb16)*64 + qr;
  unsigned short* op = O + ((size_t)b*2048 + s)*1024 + h*64 + dq;
  uint2 out; out.x = cvt_pk2(r0, r1); out.y = cvt_pk2(r2, r3);
  *(uint2*)op = out;
}

// ---------------- merge two cross bf16 (o) + f32 l partials (all rows) ----------------
__global__ __launch_bounds__(256) void attn_merge_x(
    const unsigned short* __restrict__ pob, const float* __restrict__ ml,
    unsigned short* __restrict__ O)
{
  int gid = blockIdx.x*256 + threadIdx.x;
  int row = gid>>4, dq = (gid&15)*4;
  float l0 = ml[row], l1 = ml[65536 + row];
  float inv = 1.f / (l0 + l1);
  ushort4 u0 = *(const ushort4*)(pob + (size_t)row*64 + dq);
  ushort4 u1 = *(const ushort4*)(pob + 4194304 + (size_t)row*64 + dq);
  float r0 = (b2f(u0.x) + b2f(u1.x))*inv;
  float r1 = (b2f(u0.y) + b2f(u1.y))*inv;
  float r2 = (b2f(u0.z) + b2f(u1.z))*inv;
  float r3 = (b2f(u0.w) + b2f(u1.w))*inv;
  int bh = row>>11, s = row&2047;
  int b = bh>>4, h = bh&15;
  unsigned short* op = O + ((size_t)b*2048 + s)*1024 + h*64 + dq;
  uint2 out; out.x = cvt_pk2(r0, r1); out.y = cvt_pk2(r2, r3);
  *(uint2*)op = out;
}

// ---------------- 3-way add + layernorm (ddof=1, eps on std) ----------------
template<int OUT_F32>
__global__ __launch_bounds__(256) void add_ln3(
    const unsigned short* __restrict__ a0, const unsigned short* __restrict__ a1,
    const unsigned short* __restrict__ r,
    const float* __restrict__ g, const float* __restrict__ be, void* outp)
{
  const int row = blockIdx.x, tid = threadIdx.x;
  const size_t base = (size_t)row*1024 + tid*4;
  ushort4 va = *(const ushort4*)(a0 + base);
  ushort4 vb_ = *(const ushort4*)(a1 + base);
  ushort4 vr = *(const ushort4*)(r + base);
  float x[4];
  x[0] = b2f(va.x)+b2f(vb_.x)+b2f(vr.x);
  x[1] = b2f(va.y)+b2f(vb_.y)+b2f(vr.y);
  x[2] = b2f(va.z)+b2f(vb_.z)+b2f(vr.z);
  x[3] = b2f(va.w)+b2f(vb_.w)+b2f(vr.w);
  float s = x[0]+x[1]+x[2]+x[3];
  float ss = x[0]*x[0]+x[1]*x[1]+x[2]*x[2]+x[3]*x[3];
  #pragma unroll
  for (int d=1;d<64;d<<=1){ s += __shfl_xor(s,d,64); ss += __shfl_xor(ss,d,64); }
  __shared__ float rs[4], rss[4];
  int wave = tid>>6, lane = tid&63;
  if (lane==0){ rs[wave]=s; rss[wave]=ss; }
  __syncthreads();
  s = rs[0]+rs[1]+rs[2]+rs[3];
  ss = rss[0]+rss[1]+rss[2]+rss[3];
  float mean = s*(1.f/1024.f);
  float var = (ss - 1024.f*mean*mean)*(1.f/1023.f);
  float sd = sqrtf(fmaxf(var,0.f));
  float inv = 1.f/(sd + 1e-5f);
  float4 vg = *(const float4*)(g + tid*4);
  float4 vbe = *(const float4*)(be + tid*4);
  float o0 = (x[0]-mean)*inv*vg.x+vbe.x;
  float o1 = (x[1]-mean)*inv*vg.y+vbe.y;
  float o2 = (x[2]-mean)*inv*vg.z+vbe.z;
  float o3 = (x[3]-mean)*inv*vg.w+vbe.w;
  if (OUT_F32){
    float4 vo; vo.x=o0; vo.y=o1; vo.z=o2; vo.w=o3;
    *(float4*)((float*)outp + base) = vo;
  } else {
    uint2 vo; vo.x = cvt_pk2(o0,o1); vo.y = cvt_pk2(o2,o3);
    *(uint2*)((unsigned short*)outp + base) = vo;
  }
}

extern "C" void kernel_launch(void* const* d_in, const int* in_sizes, int n_in,
                              void* d_out, int out_size, void* d_ws, size_t ws_size,
                              hipStream_t stream)
{
  typedef const float* cf;
  cf X   = (cf)d_in[0],  y   = (cf)d_in[1];
  cf wq1 = (cf)d_in[2],  bq1 = (cf)d_in[3],  wk1 = (cf)d_in[4],  bk1 = (cf)d_in[5];
  cf wv1 = (cf)d_in[6],  bv1 = (cf)d_in[7],  wo1 = (cf)d_in[8],  bo1 = (cf)d_in[9];
  cf wq2 = (cf)d_in[10], bq2 = (cf)d_in[11], wk2 = (cf)d_in[12], bk2 = (cf)d_in[13];
  cf wv2 = (cf)d_in[14], bv2 = (cf)d_in[15], wo2 = (cf)d_in[16], bo2 = (cf)d_in[17];
  cf wf1 = (cf)d_in[18], bf1 = (cf)d_in[19], wf2 = (cf)d_in[20], bf2 = (cf)d_in[21];
  cf g1  = (cf)d_in[22], be1 = (cf)d_in[23], g2  = (cf)d_in[24], be2 = (cf)d_in[25];
  cf g3  = (cf)d_in[26], be3 = (cf)d_in[27];

  char* ws = (char*)d_ws;
  const size_t MB = 1u<<20;
  unsigned short* wq1t = (unsigned short*)(ws + 0*MB);
  unsigned short* wk1t = (unsigned short*)(ws + 2*MB);
  unsigned short* wv1t = (unsigned short*)(ws + 4*MB);
  unsigned short* wo1t = (unsigned short*)(ws + 6*MB);
  unsigned short* wq2t = (unsigned short*)(ws + 8*MB);
  unsigned short* wk2t = (unsigned short*)(ws + 10*MB);
  unsigned short* wv2t = (unsigned short*)(ws + 12*MB);
  unsigned short* wo2t = (unsigned short*)(ws + 14*MB);
  unsigned short* wf1t = (unsigned short*)(ws + 16*MB);
  unsigned short* wf2t = (unsigned short*)(ws + 24*MB);
  unsigned short* Qb   = (unsigned short*)(ws + 32*MB);
  unsigned short* Kb   = (unsigned short*)(ws + 40*MB);
  unsigned short* Vtb  = (unsigned short*)(ws + 48*MB);
  unsigned short* attno= (unsigned short*)(ws + 56*MB);
  unsigned short* hbuf = (unsigned short*)(ws + 32*MB);   // stage C only (32-64MB)
  unsigned short* part = (unsigned short*)(ws + 64*MB);   // GEMM partials (2x8MB)
  float*          poF  = (float*)(ws + 64*MB);            // causal f32 partials (2x8MB)
  unsigned short* pobF = (unsigned short*)(ws + 64*MB);   // cross bf16 partials (2x8MB)
  float*          mlF  = (float*)(ws + 80*MB);            // causal l (256KB)
  unsigned short* x1b  = (unsigned short*)(ws + 80*MB);   // overwrites mlF after merge
  unsigned short* slot = (unsigned short*)(ws + 88*MB);   // yb -> Xb -> (mlX / x2b)
  unsigned short* yb = slot, *Xb = slot, *x2b = slot;
  float*          mlX  = (float*)(ws + 88*MB);            // cross l (512KB, over dead Xb)

  dim3 blk(256);
  const int NTOK = 2*2048*1024;
  cvt_f32_bf16<<<NTOK/1024, blk, 0, stream>>>(y, yb, NTOK);

  {
    TransAll tp;
    const float* Ws[10]   = {wq1,wk1,wv1,wo1,wq2,wk2,wv2,wo2,wf1,wf2};
    unsigned short* Ts[10]= {wq1t,wk1t,wv1t,wo1t,wq2t,wk2t,wv2t,wo2t,wf1t,wf2t};
    for (int i=0;i<10;i++){
      tp.W[i]=Ws[i]; tp.Wt[i]=Ts[i];
      tp.K[i] = (i==9)?4096:1024;
      tp.N[i] = (i==8)?4096:1024;
      tp.swapxy[i] = (i==9)?1:0;
    }
    transpose_cvt_all<<<dim3(128,32,10), blk, 0, stream>>>(tp);
  }

  dim3 gqkv(24,32);        // fused QKV 128^2: 768 blocks
  dim3 gs(8,32,2);         // N=1024 split-K2 128^2: 512 blocks
  dim3 gff1(32,32,1);      // FFN1 128^2: 1024 blocks
  dim3 gac(48,16,2);       // causal attn split: 1536 blocks (QB=64, proven)
  dim3 gax(32,16,2);       // cross attn QB=128 split-K2: 1024 blocks

  // ---- stage A: causal self-attention on y ----
  {
    QKVArgs a1;
    a1.Aw[0]=yb; a1.Aw[1]=yb; a1.Aw[2]=yb;
    a1.bias[0]=bq1; a1.bias[1]=bk1; a1.bias[2]=bv1;
    a1.out[0]=Qb; a1.out[1]=Kb; a1.out[2]=Vtb;
    gemm_qkv<<<gqkv, blk, 0, stream>>>(wq1t, a1, 4096, 1024);
  }
  attn_causal<<<gac, blk, 0, stream>>>(Qb, Kb, Vtb, attno, poF, mlF);
  attn_merge<<<2048, blk, 0, stream>>>(poF, mlF, attno);
  gemm_bt<0><<<gs, blk, 0, stream>>>(attno, wo1t, bo1, part, 4096, 1024, 512, 1024, 1024);
  add_ln3<0><<<4096, blk, 0, stream>>>(part, part+4194304, yb, g1, be1, x1b);

  // ---- stage B: cross-attention (Q from x1b, K/V from X) ----
  cvt_f32_bf16<<<NTOK/1024, blk, 0, stream>>>(X, Xb, NTOK);
  {
    QKVArgs a2;
    a2.Aw[0]=x1b; a2.Aw[1]=Xb; a2.Aw[2]=Xb;
    a2.bias[0]=bq2; a2.bias[1]=bk2; a2.bias[2]=bv2;
    a2.out[0]=Qb; a2.out[1]=Kb; a2.out[2]=Vtb;
    gemm_qkv<<<gqkv, blk, 0, stream>>>(wq2t, a2, 4096, 1024);
  }
  attn_cross2<<<gax, blk, 0, stream>>>(Qb, Kb, Vtb, pobF, mlX);
  attn_merge_x<<<4096, blk, 0, stream>>>(pobF, mlX, attno);
  gemm_bt<0><<<gs, blk, 0, stream>>>(attno, wo2t, bo2, part, 4096, 1024, 512, 1024, 1024);
  add_ln3<0><<<4096, blk, 0, stream>>>(part, part+4194304, x1b, g2, be2, x2b);

  // ---- stage C: FFN ----
  gemm_bt<1><<<gff1, blk, 0, stream>>>(x2b, wf1t, bf1, hbuf, 4096, 4096, 1024, 1024, 1024);
  gemm_bt<0><<<gs, blk, 0, stream>>>(hbuf, wf2t, bf2, part, 4096, 1024, 2048, 4096, 4096);
  add_ln3<1><<<4096, blk, 0, stream>>>(part, part+4194304, x2b, g3, be3, d_out);
}